// Round 5
// baseline (341.479 us; speedup 1.0000x reference)
//
#include <hip/hip_runtime.h>
#include <hip/hip_bf16.h>

#define L2E 1.44269504088896340f
#define LN2 0.69314718055994531f

typedef __bf16 bf16x8 __attribute__((ext_vector_type(8)));
typedef __bf16 bf16x4 __attribute__((ext_vector_type(4)));
typedef float f32x4 __attribute__((ext_vector_type(4)));

__device__ __forceinline__ float fexp2(float x){ return __builtin_amdgcn_exp2f(x); }
__device__ __forceinline__ float flog2(float x){ return __builtin_amdgcn_logf(x); }
__device__ __forceinline__ float frcp(float x){ return __builtin_amdgcn_rcpf(x); }
__device__ __forceinline__ float fsigmoid(float x){ return frcp(1.f + fexp2(-x*L2E)); }
__device__ __forceinline__ float fsoftplus(float x){
  float sp = flog2(1.f + fexp2(x*L2E))*LN2;
  return (x > 15.f) ? x : sp;
}
__device__ __forceinline__ float ftanh_(float x){
  x = fminf(fmaxf(x, -10.f), 10.f);
  float e = fexp2(2.f*L2E*x);
  return (e - 1.f)*frcp(e + 1.f);
}

#define NB 32
#define LS 577
#define DM 192
#define DI 384
#define BL 18464      /* NB*LS */
#define M2T 36928     /* 2*BL */
#define T_CH 19
#define N_CH 32

// ---------------- prep: bf16 casts + alog2 ----------------
__global__ __launch_bounds__(256) void k_prep(
    const float* __restrict__ x,
    const float* __restrict__ fw_in, const float* __restrict__ bw_in,
    const float* __restrict__ fw_out, const float* __restrict__ bw_out,
    const float* __restrict__ fw_xp, const float* __restrict__ bw_xp,
    const float* __restrict__ fw_al, const float* __restrict__ bw_al,
    __hip_bfloat16* __restrict__ xbf, __hip_bfloat16* __restrict__ wcat,
    __hip_bfloat16* __restrict__ wout, __hip_bfloat16* __restrict__ xpp,
    float* __restrict__ alog2)
{
  const int S0 = 3545088;            // xbf  (BL*192)
  const int S1 = S0 + 294912;        // wcat (1536*192)
  const int S2 = S1 + 147456;        // wout (192*768)
  const int S3 = S2 + 24576;         // xpp  (2*32*384)
  const int S4 = S3 + 6144;          // alog2 (2*384*8)
  int idx = blockIdx.x*256 + threadIdx.x;
  if (idx < S0) {
    xbf[idx] = __float2bfloat16(x[idx]);
  } else if (idx < S1) {
    int i = idx - S0; int r = i/192, k = i - r*192;
    float v = (r < 768) ? fw_in[r*192+k] : bw_in[(r-768)*192+k];
    wcat[i] = __float2bfloat16(v);
  } else if (idx < S2) {
    int i = idx - S1; int o = i/768, k = i - o*768;
    float v = 0.5f * ((k < 384) ? fw_out[o*384+k] : bw_out[o*384+(k-384)]);
    wout[i] = __float2bfloat16(v);
  } else if (idx < S3) {
    int i = idx - S2; int d = i/12288; int rr = i - d*12288;
    int n = rr/384, k = rr - n*384;
    const float* xp = d ? bw_xp : fw_xp;
    float v = (n < 28) ? xp[n*384+k] : 0.f;
    xpp[i] = __float2bfloat16(v);
  } else if (idx < S4) {
    int i = idx - S3;
    const float* al = (i < 3072) ? fw_al : bw_al;
    int j = (i < 3072) ? i : (i - 3072);
    alog2[i] = -fexp2(al[j]*L2E) * L2E;   // (-exp(A_log)) * log2(e)
  }
}

// ---------------- GEMM1: LDS-staged 128x128 block tile, K=192 in two 96-halves ----------
#define G1_LDA 104    /* 96 + 8 pad, elems */
#define G1_LDO 136    /* 128 + 8 pad, elems */
__global__ __launch_bounds__(256) void k_gemm1(const __hip_bfloat16* __restrict__ A,
                                               const __hip_bfloat16* __restrict__ Bw,
                                               __hip_bfloat16* __restrict__ xg,
                                               __hip_bfloat16* __restrict__ zsb)
{
  __shared__ __align__(16) __bf16 smem[26624];   // 53248 B: A[128*104] + B[128*104]
  __bf16* ldsA = smem;
  __bf16* ldsB = smem + 128*G1_LDA;

  const int t = threadIdx.x;
  const int tm = blockIdx.x / 12, tn = blockIdx.x - tm*12;
  const int m0 = tm*128, n0 = tn*128;
  const int w = t >> 6, lane = t & 63;
  const int wr = (w >> 1)*64, wc = (w & 1)*64;
  const int r = lane & 15, q = lane >> 4;

  f32x4 acc[4][4];
  #pragma unroll
  for (int a=0;a<4;++a)
    #pragma unroll
    for (int b=0;b<4;++b) acc[a][b] = (f32x4){0.f,0.f,0.f,0.f};

  #pragma unroll
  for (int h=0; h<2; ++h) {
    if (h) __syncthreads();
    #pragma unroll
    for (int j=0;j<6;++j) {
      int cid = t + 256*j;               // 0..1535
      int row = cid/12; int c8 = (cid - row*12)*8;
      int gr = m0 + row; if (gr > BL-1) gr = BL-1;
      bf16x8 va = *(const bf16x8*)(A + (size_t)gr*192 + h*96 + c8);
      *(bf16x8*)(ldsA + row*G1_LDA + c8) = va;
      bf16x8 vb = *(const bf16x8*)(Bw + (size_t)(n0+row)*192 + h*96 + c8);
      *(bf16x8*)(ldsB + row*G1_LDA + c8) = vb;
    }
    __syncthreads();
    #pragma unroll
    for (int kc=0; kc<96; kc+=32) {
      bf16x8 af[4], bfv[4];
      #pragma unroll
      for (int mi=0; mi<4; ++mi)
        af[mi] = *(const bf16x8*)(ldsA + (wr + mi*16 + r)*G1_LDA + q*8 + kc);
      #pragma unroll
      for (int ni=0; ni<4; ++ni)
        bfv[ni] = *(const bf16x8*)(ldsB + (wc + ni*16 + r)*G1_LDA + q*8 + kc);
      #pragma unroll
      for (int mi=0; mi<4; ++mi)
        #pragma unroll
        for (int ni=0; ni<4; ++ni)
          acc[mi][ni] = __builtin_amdgcn_mfma_f32_16x16x32_bf16(af[mi], bfv[ni], acc[mi][ni], 0,0,0);
    }
  }

  const int cat = tn/3;                   // 0:fw_x 1:fw_z 2:bw_x 3:bw_z
  const int cbase = (tn - cat*3)*128;
  const int d = cat >> 1, isz = cat & 1;
  __syncthreads();
  __bf16* ldsO = smem;
  #pragma unroll
  for (int mi=0; mi<4; ++mi)
    #pragma unroll
    for (int ni=0; ni<4; ++ni)
      #pragma unroll
      for (int rg=0; rg<4; ++rg) {
        int row = wr + mi*16 + q*4 + rg;
        int col = wc + ni*16 + r;
        float v = acc[mi][ni][rg];
        if (isz) v = v * fsigmoid(v);
        ldsO[row*G1_LDO + col] = (__bf16)v;
      }
  __syncthreads();
  __hip_bfloat16* dst = (isz ? zsb : xg) + (size_t)(d*BL)*384 + cbase;
  const int c8 = (t & 15)*8;
  #pragma unroll
  for (int it=0; it<8; ++it) {
    int row = (t >> 4) + it*16;
    int grow = m0 + row;
    if (grow < BL) {
      bf16x8 v = *(const bf16x8*)(ldsO + row*G1_LDO + c8);
      *(bf16x8*)(dst + (size_t)grow*384 + c8) = v;
    }
  }
}

// ---------------- conv + SiLU: xg -> xcs (bf16), 4 channels/thread ----------------
__global__ __launch_bounds__(256) void k_conv(const __hip_bfloat16* __restrict__ xg,
                                              __hip_bfloat16* __restrict__ xcs,
                                              const float* __restrict__ fw_cw, const float* __restrict__ fw_cb,
                                              const float* __restrict__ bw_cw, const float* __restrict__ bw_cb)
{
  int idx = blockIdx.x*256 + threadIdx.x;       // < 2*BL*96
  int token = idx / 96; int g = idx - token*96; int c0 = g*4;
  int d = token / BL; int r2 = token - d*BL;
  int b = r2 / LS; int i = r2 - b*LS;
  const float* cwp = (d ? bw_cw : fw_cw);
  const float* cbp = (d ? bw_cb : fw_cb);
  f32x4 w0 = *(const f32x4*)(cwp + (c0+0)*4);
  f32x4 w1 = *(const f32x4*)(cwp + (c0+1)*4);
  f32x4 w2 = *(const f32x4*)(cwp + (c0+2)*4);
  f32x4 w3 = *(const f32x4*)(cwp + (c0+3)*4);
  f32x4 accv = *(const f32x4*)(cbp + c0);
  const __hip_bfloat16* base = xg + ((size_t)(d*BL + b*LS))*384 + c0;
  #pragma unroll
  for (int j=0;j<4;++j) {
    int iw = d ? (i+3-j) : (i-3+j);
    bool valid = d ? (iw < LS) : (iw >= 0);
    if (valid) {
      bf16x4 xv = *(const bf16x4*)(base + (size_t)iw*384);
      f32x4 wj = (f32x4){w0[j], w1[j], w2[j], w3[j]};
      #pragma unroll
      for (int ch=0; ch<4; ++ch) accv[ch] += wj[ch]*(float)xv[ch];
    }
  }
  bf16x4 outv;
  #pragma unroll
  for (int ch=0; ch<4; ++ch) {
    float s = accv[ch]*fsigmoid(accv[ch]);
    outv[ch] = (__bf16)s;
  }
  *(bf16x4*)(xcs + (size_t)token*384 + c0) = outv;
}

// ---------------- GEMM dt_bc: (M=36928,N=32,K=384), tanh epilogue, scan-order store ----------------
__global__ __launch_bounds__(256) void k_dtbc(const __hip_bfloat16* __restrict__ A,
                                              const __hip_bfloat16* __restrict__ xpp,
                                              float* __restrict__ dtbc)
{
  const int wid = blockIdx.x*4 + (threadIdx.x >> 6);
  if (wid >= 1154) return;
  const int lane = threadIdx.x & 63;
  const int m0 = wid*32;
  const int r = lane & 15, q = lane >> 4;
  const int d = (m0 >= BL) ? 1 : 0;
  const __hip_bfloat16* Bp = xpp + (size_t)d*32*384;
  f32x4 acc[2][2];
  #pragma unroll
  for (int a=0;a<2;++a)
    #pragma unroll
    for (int b=0;b<2;++b) acc[a][b] = (f32x4){0.f,0.f,0.f,0.f};
  const __hip_bfloat16* Ab = A + (size_t)(m0 + r)*384 + q*8;
  const __hip_bfloat16* Bb = Bp + (size_t)r*384 + q*8;
  #pragma unroll
  for (int kc = 0; kc < 384; kc += 32) {
    bf16x8 af0 = *(const bf16x8*)(Ab + kc);
    bf16x8 af1 = *(const bf16x8*)(Ab + 16*384 + kc);
    bf16x8 bf0 = *(const bf16x8*)(Bb + kc);
    bf16x8 bf1 = *(const bf16x8*)(Bb + 16*384 + kc);
    acc[0][0] = __builtin_amdgcn_mfma_f32_16x16x32_bf16(af0, bf0, acc[0][0], 0,0,0);
    acc[0][1] = __builtin_amdgcn_mfma_f32_16x16x32_bf16(af0, bf1, acc[0][1], 0,0,0);
    acc[1][0] = __builtin_amdgcn_mfma_f32_16x16x32_bf16(af1, bf0, acc[1][0], 0,0,0);
    acc[1][1] = __builtin_amdgcn_mfma_f32_16x16x32_bf16(af1, bf1, acc[1][1], 0,0,0);
  }
  #pragma unroll
  for (int mi=0; mi<2; ++mi)
    #pragma unroll
    for (int ni=0; ni<2; ++ni)
      #pragma unroll
      for (int rg=0; rg<4; ++rg) {
        int n = ni*16 + r;
        if (n < 28) {
          int m = m0 + mi*16 + q*4 + rg;
          float v = acc[mi][ni][rg];
          if (n >= 12) v = ftanh_(v);
          int r2 = m - d*BL; int b = r2 / LS; int i = r2 - b*LS;
          int ts = d ? (LS-1-i) : i;
          dtbc[((size_t)((d*NB + b)*LS + ts))*28 + n] = v;
        }
      }
}

// ---------------- scan pass 1: per-chunk decay product P and partial state S ----------------
// grid: 384 dbc * 8 kc-tiles; block = 4 waves, wave w handles kc = tile*4 + w
__global__ __launch_bounds__(256) void k_scan1(const __hip_bfloat16* __restrict__ xcs,
                                              const float* __restrict__ dtbc,
                                              const float* __restrict__ fw_dtw, const float* __restrict__ fw_dtb,
                                              const float* __restrict__ bw_dtw, const float* __restrict__ bw_dtb,
                                              const float* __restrict__ alog2,
                                              float* __restrict__ ps)
{
  const int t = threadIdx.x;
  const int w = t >> 6, lane = t & 63;
  const int dbc = blockIdx.x >> 3;
  const int kc = (blockIdx.x & 7)*4 + w;
  const int gcid = dbc*N_CH + kc;
  const int cchunk = dbc % 6; const int db = dbc / 6;
  const int b = db & 31; const int d = db >> 5;
  const int c = cchunk*64 + lane;

  float* pp = ps + ((size_t)gcid*16)*64 + lane;
  const int ts0 = kc*T_CH;
  if (ts0 >= LS) {   // empty tail chunk: identity
    #pragma unroll
    for (int s=0;s<8;++s) pp[s*64] = 1.f;
    #pragma unroll
    for (int s=0;s<8;++s) pp[(8+s)*64] = 0.f;
    return;
  }
  const int ts1 = (ts0 + T_CH < LS) ? (ts0 + T_CH) : LS;

  const float* dtwp = (d ? bw_dtw : fw_dtw) + c*12;
  float dtw[12];
  #pragma unroll
  for (int r2=0;r2<12;++r2) dtw[r2] = dtwp[r2];
  const float dtb = (d ? bw_dtb : fw_dtb)[c];
  float al[8];
  const float* alp = alog2 + ((size_t)(d*384 + c))*8;
  #pragma unroll
  for (int s=0;s<8;++s) al[s] = alp[s];

  const float* dtbase = dtbc + ((size_t)((d*NB+b)*LS))*28;
  const __hip_bfloat16* xcb = xcs + ((size_t)(d*BL + b*LS))*384 + c;

  float P[8], S[8];
  #pragma unroll
  for (int s=0;s<8;++s){ P[s]=1.f; S[s]=0.f; }

  float nb[20]; float xnb;
  {
    const float* p0 = dtbase + (size_t)ts0*28;
    #pragma unroll
    for (int k=0;k<20;++k) nb[k] = p0[k];
    int i = d ? (LS-1-ts0) : ts0;
    xnb = __bfloat162float(xcb[(size_t)i*384]);
  }
  for (int ts=ts0; ts<ts1; ++ts) {
    float cur[20];
    #pragma unroll
    for (int k=0;k<20;++k) cur[k] = nb[k];
    float xt = xnb;
    if (ts+1 < ts1) {
      const float* p1 = dtbase + (size_t)(ts+1)*28;
      #pragma unroll
      for (int k=0;k<20;++k) nb[k] = p1[k];
      int i2 = d ? (LS-2-ts) : (ts+1);
      xnb = __bfloat162float(xcb[(size_t)i2*384]);
    }
    float dtr = dtb;
    #pragma unroll
    for (int r2=0;r2<12;++r2) dtr += cur[r2]*dtw[r2];
    float dt = fsoftplus(dtr) + 1e-4f;
    #pragma unroll
    for (int s=0;s<8;++s) {
      float da = fexp2(dt * al[s]);
      float tmp = cur[12+s]*xt;
      S[s] = tmp + da*(S[s]-tmp);
      P[s] *= da;
    }
  }
  #pragma unroll
  for (int s=0;s<8;++s) pp[s*64] = P[s];
  #pragma unroll
  for (int s=0;s<8;++s) pp[(8+s)*64] = S[s];
}

// ---------------- combine: stitch chunk states, emit entering state per chunk ----------------
__global__ __launch_bounds__(64) void k_comb(const float* __restrict__ ps,
                                             float* __restrict__ initst)
{
  const int dbc = blockIdx.x;
  const int lane = threadIdx.x;
  float st[8];
  #pragma unroll
  for (int s=0;s<8;++s) st[s]=0.f;
  for (int kc=0;kc<N_CH;++kc) {
    const float* pp = ps + ((size_t)(dbc*N_CH+kc)*16)*64 + lane;
    float* ip = initst + ((size_t)(dbc*N_CH+kc)*8)*64 + lane;
    #pragma unroll
    for (int s=0;s<8;++s) ip[s*64] = st[s];
    #pragma unroll
    for (int s=0;s<8;++s) {
      float P = pp[s*64], Sv = pp[(8+s)*64];
      st[s] = P*st[s] + Sv;
    }
  }
}

// ---------------- scan pass 2: full recurrence from entering state, emit y ----------------
__global__ __launch_bounds__(256) void k_scan2(const __hip_bfloat16* __restrict__ xcs,
                                              const __hip_bfloat16* __restrict__ zsb,
                                              const float* __restrict__ dtbc,
                                              const float* __restrict__ initst,
                                              const float* __restrict__ fw_dtw, const float* __restrict__ fw_dtb,
                                              const float* __restrict__ fw_D,
                                              const float* __restrict__ bw_dtw, const float* __restrict__ bw_dtb,
                                              const float* __restrict__ bw_D,
                                              const float* __restrict__ alog2,
                                              __hip_bfloat16* __restrict__ ybf)
{
  const int t = threadIdx.x;
  const int w = t >> 6, lane = t & 63;
  const int dbc = blockIdx.x >> 3;
  const int kc = (blockIdx.x & 7)*4 + w;
  const int gcid = dbc*N_CH + kc;
  const int cchunk = dbc % 6; const int db = dbc / 6;
  const int b = db & 31; const int d = db >> 5;
  const int c = cchunk*64 + lane;

  const int ts0 = kc*T_CH;
  if (ts0 >= LS) return;
  const int ts1 = (ts0 + T_CH < LS) ? (ts0 + T_CH) : LS;

  const float* dtwp = (d ? bw_dtw : fw_dtw) + c*12;
  float dtw[12];
  #pragma unroll
  for (int r2=0;r2<12;++r2) dtw[r2] = dtwp[r2];
  const float dtb = (d ? bw_dtb : fw_dtb)[c];
  const float Dc  = (d ? bw_D : fw_D)[c];
  float al[8];
  const float* alp = alog2 + ((size_t)(d*384 + c))*8;
  #pragma unroll
  for (int s=0;s<8;++s) al[s] = alp[s];

  float st[8];
  {
    const float* ip = initst + ((size_t)gcid*8)*64 + lane;
    #pragma unroll
    for (int s=0;s<8;++s) st[s] = ip[s*64];
  }

  const float* dtbase = dtbc + ((size_t)((d*NB+b)*LS))*28;
  const __hip_bfloat16* xcb = xcs + ((size_t)(d*BL + b*LS))*384 + c;
  const __hip_bfloat16* zcb = zsb + ((size_t)(d*BL + b*LS))*384 + c;
  __hip_bfloat16* ybase = ybf + (size_t)(b*LS)*768 + d*384 + c;

  float nb[28]; float xnb, znb;
  {
    const float* p0 = dtbase + (size_t)ts0*28;
    #pragma unroll
    for (int k=0;k<28;++k) nb[k] = p0[k];
    int i = d ? (LS-1-ts0) : ts0;
    xnb = __bfloat162float(xcb[(size_t)i*384]);
    znb = __bfloat162float(zcb[(size_t)i*384]);
  }
  for (int ts=ts0; ts<ts1; ++ts) {
    float cur[28];
    #pragma unroll
    for (int k=0;k<28;++k) cur[k] = nb[k];
    float xt = xnb, zs = znb;
    int i = d ? (LS-1-ts) : ts;
    if (ts+1 < ts1) {
      const float* p1 = dtbase + (size_t)(ts+1)*28;
      #pragma unroll
      for (int k=0;k<28;++k) nb[k] = p1[k];
      int i2 = d ? (LS-2-ts) : (ts+1);
      xnb = __bfloat162float(xcb[(size_t)i2*384]);
      znb = __bfloat162float(zcb[(size_t)i2*384]);
    }
    float dtr = dtb;
    #pragma unroll
    for (int r2=0;r2<12;++r2) dtr += cur[r2]*dtw[r2];
    float dt = fsoftplus(dtr) + 1e-4f;
    float y = Dc * xt;
    #pragma unroll
    for (int s=0;s<8;++s) {
      float da = fexp2(dt * al[s]);
      float tmp = cur[12+s]*xt;
      st[s] = tmp + da*(st[s]-tmp);
      y += st[s]*cur[20+s];
    }
    ybase[(size_t)i*768] = __float2bfloat16(y*zs);
  }
}

// ---------------- GEMM2: out = ycat @ woutcat^T  (M=18464,N=192,K=768) ----------------
__global__ __launch_bounds__(256) void k_gemm2(const __hip_bfloat16* __restrict__ A,
                                               const __hip_bfloat16* __restrict__ Bw,
                                               float* __restrict__ C)
{
  const int wid = blockIdx.x*4 + (threadIdx.x >> 6);
  if (wid >= 1731) return;
  const int lane = threadIdx.x & 63;
  const int tm = wid / 3, tn = wid - tm*3;
  const int m0 = tm*32, n0 = tn*64;
  const int r = lane & 15, q = lane >> 4;
  f32x4 acc[2][4];
  #pragma unroll
  for (int a=0;a<2;++a)
    #pragma unroll
    for (int b=0;b<4;++b) acc[a][b] = (f32x4){0.f,0.f,0.f,0.f};
  const __hip_bfloat16* Ab = A + (size_t)(m0 + r)*768 + q*8;
  const __hip_bfloat16* Bb = Bw + (size_t)(n0 + r)*768 + q*8;
  #pragma unroll 4
  for (int kc = 0; kc < 768; kc += 32) {
    bf16x8 af0 = *(const bf16x8*)(Ab + kc);
    bf16x8 af1 = *(const bf16x8*)(Ab + 16*768 + kc);
    bf16x8 bf0 = *(const bf16x8*)(Bb + kc);
    bf16x8 bf1 = *(const bf16x8*)(Bb + 16*768 + kc);
    bf16x8 bf2 = *(const bf16x8*)(Bb + 32*768 + kc);
    bf16x8 bf3 = *(const bf16x8*)(Bb + 48*768 + kc);
    acc[0][0] = __builtin_amdgcn_mfma_f32_16x16x32_bf16(af0, bf0, acc[0][0], 0,0,0);
    acc[0][1] = __builtin_amdgcn_mfma_f32_16x16x32_bf16(af0, bf1, acc[0][1], 0,0,0);
    acc[0][2] = __builtin_amdgcn_mfma_f32_16x16x32_bf16(af0, bf2, acc[0][2], 0,0,0);
    acc[0][3] = __builtin_amdgcn_mfma_f32_16x16x32_bf16(af0, bf3, acc[0][3], 0,0,0);
    acc[1][0] = __builtin_amdgcn_mfma_f32_16x16x32_bf16(af1, bf0, acc[1][0], 0,0,0);
    acc[1][1] = __builtin_amdgcn_mfma_f32_16x16x32_bf16(af1, bf1, acc[1][1], 0,0,0);
    acc[1][2] = __builtin_amdgcn_mfma_f32_16x16x32_bf16(af1, bf2, acc[1][2], 0,0,0);
    acc[1][3] = __builtin_amdgcn_mfma_f32_16x16x32_bf16(af1, bf3, acc[1][3], 0,0,0);
  }
  #pragma unroll
  for (int mi=0; mi<2; ++mi)
    #pragma unroll
    for (int ni=0; ni<4; ++ni)
      #pragma unroll
      for (int rg=0; rg<4; ++rg) {
        int row = m0 + mi*16 + q*4 + rg;
        int col = n0 + ni*16 + r;
        C[(size_t)row*192 + col] = acc[mi][ni][rg];
      }
}

extern "C" void kernel_launch(void* const* d_in, const int* in_sizes, int n_in,
                              void* d_out, int out_size, void* d_ws, size_t ws_size,
                              hipStream_t stream) {
  const float* x        = (const float*)d_in[0];
  const float* fw_in_w  = (const float*)d_in[1];
  const float* fw_cw    = (const float*)d_in[2];
  const float* fw_cb    = (const float*)d_in[3];
  const float* fw_xp    = (const float*)d_in[4];
  const float* fw_dtw   = (const float*)d_in[5];
  const float* fw_dtb   = (const float*)d_in[6];
  const float* fw_al    = (const float*)d_in[7];
  const float* fw_D     = (const float*)d_in[8];
  const float* fw_ow    = (const float*)d_in[9];
  const float* bw_in_w  = (const float*)d_in[10];
  const float* bw_cw    = (const float*)d_in[11];
  const float* bw_cb    = (const float*)d_in[12];
  const float* bw_xp    = (const float*)d_in[13];
  const float* bw_dtw   = (const float*)d_in[14];
  const float* bw_dtb   = (const float*)d_in[15];
  const float* bw_al    = (const float*)d_in[16];
  const float* bw_D     = (const float*)d_in[17];
  const float* bw_ow    = (const float*)d_in[18];

  char* ws = (char*)d_ws;
  __hip_bfloat16* xbf  = (__hip_bfloat16*)(ws + 0);
  __hip_bfloat16* wcat = (__hip_bfloat16*)(ws + 7090176);
  __hip_bfloat16* wout = (__hip_bfloat16*)(ws + 7680000);
  __hip_bfloat16* xpp  = (__hip_bfloat16*)(ws + 7974912);
  float* alog2         = (float*)(ws + 8024064);
  // scratch laid over regions dead by the time they're written:
  float* ps            = (float*)(ws + 8048640);                 // 50,331,648 B -> 58,380,288
  float* initst        = (float*)(ws + 58380288);                // 25,165,824 B -> 83,546,112 (over dead xg region; xg dead after k_conv)
  __hip_bfloat16* ybf  = (__hip_bfloat16*)(ws + 83546112);       // 28,360,704 B -> 111,906,816
  __hip_bfloat16* xg   = (__hip_bfloat16*)(ws + 74158080);       // written by gemm1, read by conv, then dead
  __hip_bfloat16* xcs  = (__hip_bfloat16*)(ws + 121491456);
  __hip_bfloat16* zsb  = (__hip_bfloat16*)(ws + 149852160);
  float* dtbc          = (float*)(ws + 178212864);               // end 182,348,800

  hipLaunchKernelGGL(k_prep, dim3(15696), dim3(256), 0, stream,
                     x, fw_in_w, bw_in_w, fw_ow, bw_ow, fw_xp, bw_xp, fw_al, bw_al,
                     xbf, wcat, wout, xpp, alog2);
  hipLaunchKernelGGL(k_gemm1, dim3(1740), dim3(256), 0, stream, xbf, wcat, xg, zsb);
  hipLaunchKernelGGL(k_conv, dim3(13848), dim3(256), 0, stream,
                     xg, xcs, fw_cw, fw_cb, bw_cw, bw_cb);
  hipLaunchKernelGGL(k_dtbc, dim3(289), dim3(256), 0, stream, xcs, xpp, dtbc);
  hipLaunchKernelGGL(k_scan1, dim3(3072), dim3(256), 0, stream,
                     xcs, dtbc, fw_dtw, fw_dtb, bw_dtw, bw_dtb, alog2, ps);
  hipLaunchKernelGGL(k_comb, dim3(384), dim3(64), 0, stream, ps, initst);
  hipLaunchKernelGGL(k_scan2, dim3(3072), dim3(256), 0, stream,
                     xcs, zsb, dtbc, initst,
                     fw_dtw, fw_dtb, fw_D, bw_dtw, bw_dtb, bw_D, alog2, ybf);
  hipLaunchKernelGGL(k_gemm2, dim3(433), dim3(256), 0, stream, ybf, wout, (float*)d_out);
}

// Round 6
// 300.369 us; speedup vs baseline: 1.1369x; 1.1369x over previous
//
#include <hip/hip_runtime.h>
#include <hip/hip_bf16.h>

#define L2E 1.44269504088896340f
#define LN2 0.69314718055994531f

typedef __bf16 bf16x8 __attribute__((ext_vector_type(8)));
typedef __bf16 bf16x4 __attribute__((ext_vector_type(4)));
typedef float f32x4 __attribute__((ext_vector_type(4)));

__device__ __forceinline__ float fexp2(float x){ return __builtin_amdgcn_exp2f(x); }
__device__ __forceinline__ float flog2(float x){ return __builtin_amdgcn_logf(x); }
__device__ __forceinline__ float frcp(float x){ return __builtin_amdgcn_rcpf(x); }
__device__ __forceinline__ float fsigmoid(float x){ return frcp(1.f + fexp2(-x*L2E)); }
__device__ __forceinline__ float fsoftplus(float x){
  float sp = flog2(1.f + fexp2(x*L2E))*LN2;
  return (x > 15.f) ? x : sp;
}
__device__ __forceinline__ float ftanh_(float x){
  x = fminf(fmaxf(x, -10.f), 10.f);
  float e = fexp2(2.f*L2E*x);
  return (e - 1.f)*frcp(e + 1.f);
}

#define NB 32
#define LS 577
#define DM 192
#define DI 384
#define BL 18464      /* NB*LS */
#define M2T 36928     /* 2*BL */
#define T_CH 37
#define N_CH 16

// ---------------- prep: bf16 casts + alog2 ----------------
__global__ __launch_bounds__(256) void k_prep(
    const float* __restrict__ x,
    const float* __restrict__ fw_in, const float* __restrict__ bw_in,
    const float* __restrict__ fw_out, const float* __restrict__ bw_out,
    const float* __restrict__ fw_xp, const float* __restrict__ bw_xp,
    const float* __restrict__ fw_al, const float* __restrict__ bw_al,
    __hip_bfloat16* __restrict__ xbf, __hip_bfloat16* __restrict__ wcat,
    __hip_bfloat16* __restrict__ wout, __hip_bfloat16* __restrict__ xpp,
    float* __restrict__ alog2)
{
  const int S0 = 3545088;            // xbf  (BL*192)
  const int S1 = S0 + 294912;        // wcat (1536*192)
  const int S2 = S1 + 147456;        // wout (192*768)
  const int S3 = S2 + 24576;         // xpp  (2*32*384)
  const int S4 = S3 + 6144;          // alog2 (2*384*8)
  int idx = blockIdx.x*256 + threadIdx.x;
  if (idx < S0) {
    xbf[idx] = __float2bfloat16(x[idx]);
  } else if (idx < S1) {
    int i = idx - S0; int r = i/192, k = i - r*192;
    float v = (r < 768) ? fw_in[r*192+k] : bw_in[(r-768)*192+k];
    wcat[i] = __float2bfloat16(v);
  } else if (idx < S2) {
    int i = idx - S1; int o = i/768, k = i - o*768;
    float v = 0.5f * ((k < 384) ? fw_out[o*384+k] : bw_out[o*384+(k-384)]);
    wout[i] = __float2bfloat16(v);
  } else if (idx < S3) {
    int i = idx - S2; int d = i/12288; int rr = i - d*12288;
    int n = rr/384, k = rr - n*384;
    const float* xp = d ? bw_xp : fw_xp;
    float v = (n < 28) ? xp[n*384+k] : 0.f;
    xpp[i] = __float2bfloat16(v);
  } else if (idx < S4) {
    int i = idx - S3;
    const float* al = (i < 3072) ? fw_al : bw_al;
    int j = (i < 3072) ? i : (i - 3072);
    alog2[i] = -fexp2(al[j]*L2E) * L2E;   // (-exp(A_log)) * log2(e)
  }
}

// ---------------- GEMM1: LDS-staged 128x128 block tile, K=192 in two 96-halves ----------
#define G1_LDA 104    /* 96 + 8 pad, elems */
#define G1_LDO 136    /* 128 + 8 pad, elems */
__global__ __launch_bounds__(256) void k_gemm1(const __hip_bfloat16* __restrict__ A,
                                               const __hip_bfloat16* __restrict__ Bw,
                                               __hip_bfloat16* __restrict__ xg,
                                               __hip_bfloat16* __restrict__ zsb)
{
  __shared__ __align__(16) __bf16 smem[26624];   // 53248 B: A[128*104] + B[128*104]
  __bf16* ldsA = smem;
  __bf16* ldsB = smem + 128*G1_LDA;

  const int t = threadIdx.x;
  const int tm = blockIdx.x / 12, tn = blockIdx.x - tm*12;
  const int m0 = tm*128, n0 = tn*128;
  const int w = t >> 6, lane = t & 63;
  const int wr = (w >> 1)*64, wc = (w & 1)*64;
  const int r = lane & 15, q = lane >> 4;

  f32x4 acc[4][4];
  #pragma unroll
  for (int a=0;a<4;++a)
    #pragma unroll
    for (int b=0;b<4;++b) acc[a][b] = (f32x4){0.f,0.f,0.f,0.f};

  #pragma unroll
  for (int h=0; h<2; ++h) {
    if (h) __syncthreads();
    #pragma unroll
    for (int j=0;j<6;++j) {
      int cid = t + 256*j;               // 0..1535
      int row = cid/12; int c8 = (cid - row*12)*8;
      int gr = m0 + row; if (gr > BL-1) gr = BL-1;
      bf16x8 va = *(const bf16x8*)(A + (size_t)gr*192 + h*96 + c8);
      *(bf16x8*)(ldsA + row*G1_LDA + c8) = va;
      bf16x8 vb = *(const bf16x8*)(Bw + (size_t)(n0+row)*192 + h*96 + c8);
      *(bf16x8*)(ldsB + row*G1_LDA + c8) = vb;
    }
    __syncthreads();
    #pragma unroll
    for (int kc=0; kc<96; kc+=32) {
      bf16x8 af[4], bfv[4];
      #pragma unroll
      for (int mi=0; mi<4; ++mi)
        af[mi] = *(const bf16x8*)(ldsA + (wr + mi*16 + r)*G1_LDA + q*8 + kc);
      #pragma unroll
      for (int ni=0; ni<4; ++ni)
        bfv[ni] = *(const bf16x8*)(ldsB + (wc + ni*16 + r)*G1_LDA + q*8 + kc);
      #pragma unroll
      for (int mi=0; mi<4; ++mi)
        #pragma unroll
        for (int ni=0; ni<4; ++ni)
          acc[mi][ni] = __builtin_amdgcn_mfma_f32_16x16x32_bf16(af[mi], bfv[ni], acc[mi][ni], 0,0,0);
    }
  }

  const int cat = tn/3;                   // 0:fw_x 1:fw_z 2:bw_x 3:bw_z
  const int cbase = (tn - cat*3)*128;
  const int d = cat >> 1, isz = cat & 1;
  __syncthreads();
  __bf16* ldsO = smem;
  #pragma unroll
  for (int mi=0; mi<4; ++mi)
    #pragma unroll
    for (int ni=0; ni<4; ++ni)
      #pragma unroll
      for (int rg=0; rg<4; ++rg) {
        int row = wr + mi*16 + q*4 + rg;
        int col = wc + ni*16 + r;
        float v = acc[mi][ni][rg];
        if (isz) v = v * fsigmoid(v);
        ldsO[row*G1_LDO + col] = (__bf16)v;
      }
  __syncthreads();
  __hip_bfloat16* dst = (isz ? zsb : xg) + (size_t)(d*BL)*384 + cbase;
  const int c8 = (t & 15)*8;
  #pragma unroll
  for (int it=0; it<8; ++it) {
    int row = (t >> 4) + it*16;
    int grow = m0 + row;
    if (grow < BL) {
      bf16x8 v = *(const bf16x8*)(ldsO + row*G1_LDO + c8);
      *(bf16x8*)(dst + (size_t)grow*384 + c8) = v;
    }
  }
}

// ---------------- conv + SiLU: xg -> xcs (bf16), 4 channels/thread ----------------
__global__ __launch_bounds__(256) void k_conv(const __hip_bfloat16* __restrict__ xg,
                                              __hip_bfloat16* __restrict__ xcs,
                                              const float* __restrict__ fw_cw, const float* __restrict__ fw_cb,
                                              const float* __restrict__ bw_cw, const float* __restrict__ bw_cb)
{
  int idx = blockIdx.x*256 + threadIdx.x;       // < 2*BL*96
  int token = idx / 96; int g = idx - token*96; int c0 = g*4;
  int d = token / BL; int r2 = token - d*BL;
  int b = r2 / LS; int i = r2 - b*LS;
  const float* cwp = (d ? bw_cw : fw_cw);
  const float* cbp = (d ? bw_cb : fw_cb);
  f32x4 w0 = *(const f32x4*)(cwp + (c0+0)*4);
  f32x4 w1 = *(const f32x4*)(cwp + (c0+1)*4);
  f32x4 w2 = *(const f32x4*)(cwp + (c0+2)*4);
  f32x4 w3 = *(const f32x4*)(cwp + (c0+3)*4);
  f32x4 accv = *(const f32x4*)(cbp + c0);
  const __hip_bfloat16* base = xg + ((size_t)(d*BL + b*LS))*384 + c0;
  #pragma unroll
  for (int j=0;j<4;++j) {
    int iw = d ? (i+3-j) : (i-3+j);
    bool valid = d ? (iw < LS) : (iw >= 0);
    if (valid) {
      bf16x4 xv = *(const bf16x4*)(base + (size_t)iw*384);
      f32x4 wj = (f32x4){w0[j], w1[j], w2[j], w3[j]};
      #pragma unroll
      for (int ch=0; ch<4; ++ch) accv[ch] += wj[ch]*(float)xv[ch];
    }
  }
  bf16x4 outv;
  #pragma unroll
  for (int ch=0; ch<4; ++ch) {
    float s = accv[ch]*fsigmoid(accv[ch]);
    outv[ch] = (__bf16)s;
  }
  *(bf16x4*)(xcs + (size_t)token*384 + c0) = outv;
}

// ---------------- GEMM dt_bc: (M=36928,N=32,K=384), tanh epilogue, scan-order store ----------------
__global__ __launch_bounds__(256) void k_dtbc(const __hip_bfloat16* __restrict__ A,
                                              const __hip_bfloat16* __restrict__ xpp,
                                              float* __restrict__ dtbc)
{
  const int wid = blockIdx.x*4 + (threadIdx.x >> 6);
  if (wid >= 1154) return;
  const int lane = threadIdx.x & 63;
  const int m0 = wid*32;
  const int r = lane & 15, q = lane >> 4;
  const int d = (m0 >= BL) ? 1 : 0;
  const __hip_bfloat16* Bp = xpp + (size_t)d*32*384;
  f32x4 acc[2][2];
  #pragma unroll
  for (int a=0;a<2;++a)
    #pragma unroll
    for (int b=0;b<2;++b) acc[a][b] = (f32x4){0.f,0.f,0.f,0.f};
  const __hip_bfloat16* Ab = A + (size_t)(m0 + r)*384 + q*8;
  const __hip_bfloat16* Bb = Bp + (size_t)r*384 + q*8;
  #pragma unroll
  for (int kc = 0; kc < 384; kc += 32) {
    bf16x8 af0 = *(const bf16x8*)(Ab + kc);
    bf16x8 af1 = *(const bf16x8*)(Ab + 16*384 + kc);
    bf16x8 bf0 = *(const bf16x8*)(Bb + kc);
    bf16x8 bf1 = *(const bf16x8*)(Bb + 16*384 + kc);
    acc[0][0] = __builtin_amdgcn_mfma_f32_16x16x32_bf16(af0, bf0, acc[0][0], 0,0,0);
    acc[0][1] = __builtin_amdgcn_mfma_f32_16x16x32_bf16(af0, bf1, acc[0][1], 0,0,0);
    acc[1][0] = __builtin_amdgcn_mfma_f32_16x16x32_bf16(af1, bf0, acc[1][0], 0,0,0);
    acc[1][1] = __builtin_amdgcn_mfma_f32_16x16x32_bf16(af1, bf1, acc[1][1], 0,0,0);
  }
  #pragma unroll
  for (int mi=0; mi<2; ++mi)
    #pragma unroll
    for (int ni=0; ni<2; ++ni)
      #pragma unroll
      for (int rg=0; rg<4; ++rg) {
        int n = ni*16 + r;
        if (n < 28) {
          int m = m0 + mi*16 + q*4 + rg;
          float v = acc[mi][ni][rg];
          if (n >= 12) v = ftanh_(v);
          int r2 = m - d*BL; int b = r2 / LS; int i = r2 - b*LS;
          int ts = d ? (LS-1-i) : i;
          dtbc[((size_t)((d*NB + b)*LS + ts))*28 + n] = v;
        }
      }
}

// ---------------- scan pass 1: per-chunk decay product P and partial state S ----------------
// grid: 384 dbc * 16 kchunks; bid = dbc*16 + kc; LDS-staged dtbc tile
__global__ __launch_bounds__(64) void k_scan1(const __hip_bfloat16* __restrict__ xcs,
                                              const float* __restrict__ dtbc,
                                              const float* __restrict__ fw_dtw, const float* __restrict__ fw_dtb,
                                              const float* __restrict__ bw_dtw, const float* __restrict__ bw_dtb,
                                              const float* __restrict__ alog2,
                                              float* __restrict__ ps)
{
  __shared__ __align__(16) float sdt[T_CH*28];
  const int bid = blockIdx.x;
  const int lane = threadIdx.x;
  const int kc = bid & 15; const int dbc = bid >> 4;
  const int cchunk = dbc % 6; const int db = dbc / 6;
  const int b = db & 31; const int d = db >> 5;
  const int c = cchunk*64 + lane;

  const int ts0 = kc*T_CH;
  const int ts1 = (ts0 + T_CH < LS) ? (ts0 + T_CH) : LS;

  // cooperative stage: contiguous (ts1-ts0)*28 floats, 16B-aligned chunks
  {
    const float* src = dtbc + ((size_t)((d*NB+b)*LS + ts0))*28;
    int n4 = (ts1 - ts0)*7;                 // f32x4 count (28 = 4*7)
    for (int j = lane; j < n4; j += 64)
      *(f32x4*)(sdt + j*4) = *(const f32x4*)(src + j*4);
  }

  const float* dtwp = (d ? bw_dtw : fw_dtw) + c*12;
  float dtw[12];
  #pragma unroll
  for (int r2=0;r2<12;++r2) dtw[r2] = dtwp[r2];
  const float dtb = (d ? bw_dtb : fw_dtb)[c];
  float al[8];
  const float* alp = alog2 + ((size_t)(d*384 + c))*8;
  #pragma unroll
  for (int s=0;s<8;++s) al[s] = alp[s];

  const __hip_bfloat16* xcb = xcs + ((size_t)(d*BL + b*LS))*384 + c;

  float P[8], S[8];
  #pragma unroll
  for (int s=0;s<8;++s){ P[s]=1.f; S[s]=0.f; }

  __syncthreads();   // single-wave block: compiles to waitcnt

  float xnb;
  {
    int i = d ? (LS-1-ts0) : ts0;
    xnb = __bfloat162float(xcb[(size_t)i*384]);
  }
  for (int ts=ts0; ts<ts1; ++ts) {
    const float* cur = sdt + (ts-ts0)*28;
    float xt = xnb;
    if (ts+1 < ts1) {
      int i2 = d ? (LS-2-ts) : (ts+1);
      xnb = __bfloat162float(xcb[(size_t)i2*384]);
    }
    float dtr = dtb;
    #pragma unroll
    for (int r2=0;r2<12;++r2) dtr += cur[r2]*dtw[r2];
    float dt = fsoftplus(dtr) + 1e-4f;
    #pragma unroll
    for (int s=0;s<8;++s) {
      float da = fexp2(dt * al[s]);
      float tmp = cur[12+s]*xt;
      S[s] = tmp + da*(S[s]-tmp);
      P[s] *= da;
    }
  }
  float* pp = ps + ((size_t)bid*16)*64 + lane;
  #pragma unroll
  for (int s=0;s<8;++s) pp[s*64] = P[s];
  #pragma unroll
  for (int s=0;s<8;++s) pp[(8+s)*64] = S[s];
}

// ---------------- combine: stitch chunk states, emit entering state per chunk ----------------
__global__ __launch_bounds__(64) void k_comb(const float* __restrict__ ps,
                                             float* __restrict__ initst)
{
  const int dbc = blockIdx.x;
  const int lane = threadIdx.x;
  float st[8];
  #pragma unroll
  for (int s=0;s<8;++s) st[s]=0.f;
  for (int kc=0;kc<N_CH;++kc) {
    const float* pp = ps + ((size_t)(dbc*N_CH+kc)*16)*64 + lane;
    float* ip = initst + ((size_t)(dbc*N_CH+kc)*8)*64 + lane;
    #pragma unroll
    for (int s=0;s<8;++s) ip[s*64] = st[s];
    #pragma unroll
    for (int s=0;s<8;++s) {
      float P = pp[s*64], Sv = pp[(8+s)*64];
      st[s] = P*st[s] + Sv;
    }
  }
}

// ---------------- scan pass 2: full recurrence from entering state, emit y ----------------
__global__ __launch_bounds__(64) void k_scan2(const __hip_bfloat16* __restrict__ xcs,
                                              const __hip_bfloat16* __restrict__ zsb,
                                              const float* __restrict__ dtbc,
                                              const float* __restrict__ initst,
                                              const float* __restrict__ fw_dtw, const float* __restrict__ fw_dtb,
                                              const float* __restrict__ fw_D,
                                              const float* __restrict__ bw_dtw, const float* __restrict__ bw_dtb,
                                              const float* __restrict__ bw_D,
                                              const float* __restrict__ alog2,
                                              __hip_bfloat16* __restrict__ ybf)
{
  __shared__ __align__(16) float sdt[T_CH*28];
  const int bid = blockIdx.x;
  const int lane = threadIdx.x;
  const int kc = bid & 15; const int dbc = bid >> 4;
  const int cchunk = dbc % 6; const int db = dbc / 6;
  const int b = db & 31; const int d = db >> 5;
  const int c = cchunk*64 + lane;

  const int ts0 = kc*T_CH;
  const int ts1 = (ts0 + T_CH < LS) ? (ts0 + T_CH) : LS;

  {
    const float* src = dtbc + ((size_t)((d*NB+b)*LS + ts0))*28;
    int n4 = (ts1 - ts0)*7;
    for (int j = lane; j < n4; j += 64)
      *(f32x4*)(sdt + j*4) = *(const f32x4*)(src + j*4);
  }

  const float* dtwp = (d ? bw_dtw : fw_dtw) + c*12;
  float dtw[12];
  #pragma unroll
  for (int r2=0;r2<12;++r2) dtw[r2] = dtwp[r2];
  const float dtb = (d ? bw_dtb : fw_dtb)[c];
  const float Dc  = (d ? bw_D : fw_D)[c];
  float al[8];
  const float* alp = alog2 + ((size_t)(d*384 + c))*8;
  #pragma unroll
  for (int s=0;s<8;++s) al[s] = alp[s];

  float st[8];
  {
    const float* ip = initst + ((size_t)bid*8)*64 + lane;
    #pragma unroll
    for (int s=0;s<8;++s) st[s] = ip[s*64];
  }

  const __hip_bfloat16* xcb = xcs + ((size_t)(d*BL + b*LS))*384 + c;
  const __hip_bfloat16* zcb = zsb + ((size_t)(d*BL + b*LS))*384 + c;
  __hip_bfloat16* ybase = ybf + (size_t)(b*LS)*768 + d*384 + c;

  __syncthreads();

  float xnb, znb;
  {
    int i = d ? (LS-1-ts0) : ts0;
    xnb = __bfloat162float(xcb[(size_t)i*384]);
    znb = __bfloat162float(zcb[(size_t)i*384]);
  }
  for (int ts=ts0; ts<ts1; ++ts) {
    const float* cur = sdt + (ts-ts0)*28;
    float xt = xnb, zs = znb;
    int i = d ? (LS-1-ts) : ts;
    if (ts+1 < ts1) {
      int i2 = d ? (LS-2-ts) : (ts+1);
      xnb = __bfloat162float(xcb[(size_t)i2*384]);
      znb = __bfloat162float(zcb[(size_t)i2*384]);
    }
    float dtr = dtb;
    #pragma unroll
    for (int r2=0;r2<12;++r2) dtr += cur[r2]*dtw[r2];
    float dt = fsoftplus(dtr) + 1e-4f;
    float y = Dc * xt;
    #pragma unroll
    for (int s=0;s<8;++s) {
      float da = fexp2(dt * al[s]);
      float tmp = cur[12+s]*xt;
      st[s] = tmp + da*(st[s]-tmp);
      y += st[s]*cur[20+s];
    }
    ybase[(size_t)i*768] = __float2bfloat16(y*zs);
  }
}

// ---------------- GEMM2: out = ycat @ woutcat^T  (M=18464,N=192,K=768) ----------------
__global__ __launch_bounds__(256) void k_gemm2(const __hip_bfloat16* __restrict__ A,
                                               const __hip_bfloat16* __restrict__ Bw,
                                               float* __restrict__ C)
{
  const int wid = blockIdx.x*4 + (threadIdx.x >> 6);
  if (wid >= 1731) return;
  const int lane = threadIdx.x & 63;
  const int tm = wid / 3, tn = wid - tm*3;
  const int m0 = tm*32, n0 = tn*64;
  const int r = lane & 15, q = lane >> 4;
  f32x4 acc[2][4];
  #pragma unroll
  for (int a=0;a<2;++a)
    #pragma unroll
    for (int b=0;b<4;++b) acc[a][b] = (f32x4){0.f,0.f,0.f,0.f};
  const __hip_bfloat16* Ab = A + (size_t)(m0 + r)*768 + q*8;
  const __hip_bfloat16* Bb = Bw + (size_t)(n0 + r)*768 + q*8;
  #pragma unroll 4
  for (int kc = 0; kc < 768; kc += 32) {
    bf16x8 af0 = *(const bf16x8*)(Ab + kc);
    bf16x8 af1 = *(const bf16x8*)(Ab + 16*768 + kc);
    bf16x8 bf0 = *(const bf16x8*)(Bb + kc);
    bf16x8 bf1 = *(const bf16x8*)(Bb + 16*768 + kc);
    bf16x8 bf2 = *(const bf16x8*)(Bb + 32*768 + kc);
    bf16x8 bf3 = *(const bf16x8*)(Bb + 48*768 + kc);
    acc[0][0] = __builtin_amdgcn_mfma_f32_16x16x32_bf16(af0, bf0, acc[0][0], 0,0,0);
    acc[0][1] = __builtin_amdgcn_mfma_f32_16x16x32_bf16(af0, bf1, acc[0][1], 0,0,0);
    acc[0][2] = __builtin_amdgcn_mfma_f32_16x16x32_bf16(af0, bf2, acc[0][2], 0,0,0);
    acc[0][3] = __builtin_amdgcn_mfma_f32_16x16x32_bf16(af0, bf3, acc[0][3], 0,0,0);
    acc[1][0] = __builtin_amdgcn_mfma_f32_16x16x32_bf16(af1, bf0, acc[1][0], 0,0,0);
    acc[1][1] = __builtin_amdgcn_mfma_f32_16x16x32_bf16(af1, bf1, acc[1][1], 0,0,0);
    acc[1][2] = __builtin_amdgcn_mfma_f32_16x16x32_bf16(af1, bf2, acc[1][2], 0,0,0);
    acc[1][3] = __builtin_amdgcn_mfma_f32_16x16x32_bf16(af1, bf3, acc[1][3], 0,0,0);
  }
  #pragma unroll
  for (int mi=0; mi<2; ++mi)
    #pragma unroll
    for (int ni=0; ni<4; ++ni)
      #pragma unroll
      for (int rg=0; rg<4; ++rg) {
        int row = m0 + mi*16 + q*4 + rg;
        int col = n0 + ni*16 + r;
        C[(size_t)row*192 + col] = acc[mi][ni][rg];
      }
}

extern "C" void kernel_launch(void* const* d_in, const int* in_sizes, int n_in,
                              void* d_out, int out_size, void* d_ws, size_t ws_size,
                              hipStream_t stream) {
  const float* x        = (const float*)d_in[0];
  const float* fw_in_w  = (const float*)d_in[1];
  const float* fw_cw    = (const float*)d_in[2];
  const float* fw_cb    = (const float*)d_in[3];
  const float* fw_xp    = (const float*)d_in[4];
  const float* fw_dtw   = (const float*)d_in[5];
  const float* fw_dtb   = (const float*)d_in[6];
  const float* fw_al    = (const float*)d_in[7];
  const float* fw_D     = (const float*)d_in[8];
  const float* fw_ow    = (const float*)d_in[9];
  const float* bw_in_w  = (const float*)d_in[10];
  const float* bw_cw    = (const float*)d_in[11];
  const float* bw_cb    = (const float*)d_in[12];
  const float* bw_xp    = (const float*)d_in[13];
  const float* bw_dtw   = (const float*)d_in[14];
  const float* bw_dtb   = (const float*)d_in[15];
  const float* bw_al    = (const float*)d_in[16];
  const float* bw_D     = (const float*)d_in[17];
  const float* bw_ow    = (const float*)d_in[18];

  char* ws = (char*)d_ws;
  __hip_bfloat16* xbf  = (__hip_bfloat16*)(ws + 0);
  __hip_bfloat16* wcat = (__hip_bfloat16*)(ws + 7090176);
  __hip_bfloat16* wout = (__hip_bfloat16*)(ws + 7680000);
  __hip_bfloat16* xpp  = (__hip_bfloat16*)(ws + 7974912);
  float* alog2         = (float*)(ws + 8024064);
  float* ps            = (float*)(ws + 8048640);                 // 25.2 MB
  float* initst        = (float*)(ws + 58380288);                // 12.6 MB
  __hip_bfloat16* ybf  = (__hip_bfloat16*)(ws + 83546112);       // 28.4 MB (over dead xg tail)
  __hip_bfloat16* xg   = (__hip_bfloat16*)(ws + 74158080);       // gemm1 -> conv, then dead
  __hip_bfloat16* xcs  = (__hip_bfloat16*)(ws + 121491456);
  __hip_bfloat16* zsb  = (__hip_bfloat16*)(ws + 149852160);
  float* dtbc          = (float*)(ws + 178212864);               // end 182,348,800

  hipLaunchKernelGGL(k_prep, dim3(15696), dim3(256), 0, stream,
                     x, fw_in_w, bw_in_w, fw_ow, bw_ow, fw_xp, bw_xp, fw_al, bw_al,
                     xbf, wcat, wout, xpp, alog2);
  hipLaunchKernelGGL(k_gemm1, dim3(1740), dim3(256), 0, stream, xbf, wcat, xg, zsb);
  hipLaunchKernelGGL(k_conv, dim3(13848), dim3(256), 0, stream,
                     xg, xcs, fw_cw, fw_cb, bw_cw, bw_cb);
  hipLaunchKernelGGL(k_dtbc, dim3(289), dim3(256), 0, stream, xcs, xpp, dtbc);
  hipLaunchKernelGGL(k_scan1, dim3(6144), dim3(64), 0, stream,
                     xcs, dtbc, fw_dtw, fw_dtb, bw_dtw, bw_dtb, alog2, ps);
  hipLaunchKernelGGL(k_comb, dim3(384), dim3(64), 0, stream, ps, initst);
  hipLaunchKernelGGL(k_scan2, dim3(6144), dim3(64), 0, stream,
                     xcs, zsb, dtbc, initst,
                     fw_dtw, fw_dtb, fw_D, bw_dtw, bw_dtb, bw_D, alog2, ybf);
  hipLaunchKernelGGL(k_gemm2, dim3(433), dim3(256), 0, stream, ybf, wout, (float*)d_out);
}